// Round 5
// baseline (1145.050 us; speedup 1.0000x reference)
//
#include <hip/hip_runtime.h>

#define N_NODES 30000
#define N_EDGES 300000
#define N_TRIP 200000
#define NUM_RELS 8
#define F_RAW 128
#define DDIM 256

#define NBUCK (2 * NUM_RELS * N_NODES)                    // 480000 buckets
#define SCAN_CHUNK 1024
#define NCHUNK ((NBUCK + SCAN_CHUNK - 1) / SCAN_CHUNK)    // 469
#define NPAD (NCHUNK * SCAN_CHUNK)                        // 480256

#define NPHASE 17            // 8 fwd + 8 bwd + selfloop
#define WCAT_ELEMS (NPHASE * 8 * 4 * 4 * 64 * 8)          // 1,114,112

typedef __attribute__((ext_vector_type(8))) short short8;
typedef __attribute__((ext_vector_type(4))) float f32x4;

__device__ inline unsigned short f2bf(float f) {
  unsigned u = __builtin_bit_cast(unsigned, f);
  u = (u + 0x7FFFu + ((u >> 16) & 1u)) >> 16;
  return (unsigned short)u;
}
__device__ inline float bf2f(unsigned short s) {
  unsigned u = ((unsigned)s) << 16;
  return __builtin_bit_cast(float, u);
}

// 8 fp32 -> short8 bf16 (RNE) via packed convert
__device__ inline short8 cvt8(f32x4 lo, f32x4 hi) {
  union { unsigned u[4]; short8 s; } r;
  asm("v_cvt_pk_bf16_f32 %0, %1, %2" : "=v"(r.u[0]) : "v"(lo[0]), "v"(lo[1]));
  asm("v_cvt_pk_bf16_f32 %0, %1, %2" : "=v"(r.u[1]) : "v"(lo[2]), "v"(lo[3]));
  asm("v_cvt_pk_bf16_f32 %0, %1, %2" : "=v"(r.u[2]) : "v"(hi[0]), "v"(hi[1]));
  asm("v_cvt_pk_bf16_f32 %0, %1, %2" : "=v"(r.u[3]) : "v"(hi[2]), "v"(hi[3]));
  return r.s;
}

// ===========================================================================
// Edge bucketing (counting sort by (rel, endpoint), both directions).
// fwd bucket = r*N + dst (phase r); bwd bucket = (8+r)*N + src (phase 8+r).
// pairs[pos] = {gather_node, owner_node}.
// ===========================================================================
__global__ void zero_int_kernel(int* __restrict__ p, int n) {
  int i = blockIdx.x * blockDim.x + threadIdx.x;
  if (i < n) p[i] = 0;
}

__global__ void hist_kernel(const int* __restrict__ src,
                            const int* __restrict__ dst,
                            const int* __restrict__ et, int* __restrict__ cnt) {
  int e = blockIdx.x * blockDim.x + threadIdx.x;
  if (e >= N_EDGES) return;
  int r = et[e];
  atomicAdd(&cnt[r * N_NODES + dst[e]], 1);
  atomicAdd(&cnt[(NUM_RELS + r) * N_NODES + src[e]], 1);
}

__global__ __launch_bounds__(256) void scan1_kernel(const int* __restrict__ cnt,
                                                    int* __restrict__ offs,
                                                    int* __restrict__ bsum) {
  __shared__ int s[256];
  const int b = blockIdx.x, t = threadIdx.x;
  const int base = b * SCAN_CHUNK + t * 4;
  int4 v = *reinterpret_cast<const int4*>(&cnt[base]);
  int tsum = v.x + v.y + v.z + v.w;
  s[t] = tsum;
  __syncthreads();
  for (int off = 1; off < 256; off <<= 1) {
    int x = (t >= off) ? s[t - off] : 0;
    __syncthreads();
    s[t] += x;
    __syncthreads();
  }
  int excl = s[t] - tsum;
  offs[base + 0] = excl;
  offs[base + 1] = excl + v.x;
  offs[base + 2] = excl + v.x + v.y;
  offs[base + 3] = excl + v.x + v.y + v.z;
  if (t == 0) bsum[b] = s[255];
}

__global__ __launch_bounds__(512) void scan2_kernel(int* __restrict__ bsum) {
  __shared__ int s[512];
  const int t = threadIdx.x;
  int v = (t < NCHUNK) ? bsum[t] : 0;
  s[t] = v;
  __syncthreads();
  for (int off = 1; off < 512; off <<= 1) {
    int x = (t >= off) ? s[t - off] : 0;
    __syncthreads();
    s[t] += x;
    __syncthreads();
  }
  if (t < NCHUNK) bsum[t] = s[t] - v;
}

__global__ void scan3_kernel(int* __restrict__ offs,
                             const int* __restrict__ bsum,
                             int* __restrict__ cur) {
  int i = blockIdx.x * blockDim.x + threadIdx.x;
  if (i >= NPAD) return;
  int v = offs[i] + bsum[i / SCAN_CHUNK];
  offs[i] = v;
  if (i < NBUCK) cur[i] = v;
}

__global__ void fill_kernel(const int* __restrict__ src,
                            const int* __restrict__ dst,
                            const int* __restrict__ et, int* __restrict__ cur,
                            int2* __restrict__ pairs) {
  int e = blockIdx.x * blockDim.x + threadIdx.x;
  if (e >= N_EDGES) return;
  int r = et[e];
  int s = src[e], d = dst[e];
  int p1 = atomicAdd(&cur[r * N_NODES + d], 1);
  pairs[p1] = make_int2(s, d);
  int p2 = atomicAdd(&cur[(NUM_RELS + r) * N_NODES + s], 1);
  pairs[p2] = make_int2(d, s);
}

// ===========================================================================
// Conversions / weight prep
// ===========================================================================
__global__ void convert_bf16_kernel(const float* __restrict__ src,
                                    unsigned short* __restrict__ dst,
                                    int total) {
  const int i = blockIdx.x * blockDim.x + threadIdx.x;
  if (i < total) dst[i] = f2bf(src[i]);
}

__global__ void transpose_bf16_kernel(const float* __restrict__ src,
                                      unsigned short* __restrict__ dst,
                                      int R, int K, int N) {
  const int i = blockIdx.x * blockDim.x + threadIdx.x;
  const int total = R * K * N;
  if (i >= total) return;
  const int r = i / (K * N);
  const int rem = i - r * K * N;
  const int k = rem / N;
  const int n = rem - k * N;
  dst[(size_t)r * K * N + (size_t)n * K + k] = f2bf(src[i]);
}

// Wcat in exact per-lane B-fragment order:
// idx = ((((p*8 + t)*4 + w)*4 + ni)*64 + lane)*8 + j
// value = W_p[k][n], n = w*64 + ni*16 + (lane&15), k = t*32 + (lane>>4)*8 + j
__global__ void build_wcat_kernel(const float* __restrict__ Wf,
                                  const float* __restrict__ Wb,
                                  const float* __restrict__ Wl,
                                  unsigned short* __restrict__ dst) {
  const int i = blockIdx.x * blockDim.x + threadIdx.x;
  if (i >= WCAT_ELEMS) return;
  const int j = i & 7;
  const int lane = (i >> 3) & 63;
  const int ni = (i >> 9) & 3;
  const int wq = (i >> 11) & 3;
  const int t = (i >> 13) & 7;
  const int p = i >> 16;
  const int n = wq * 64 + ni * 16 + (lane & 15);
  const int k = t * 32 + (lane >> 4) * 8 + j;
  float v;
  if (p < 8)
    v = Wf[((size_t)p * 256 + k) * 256 + n];
  else if (p < 16)
    v = Wb[((size_t)(p - 8) * 256 + k) * 256 + n];
  else
    v = Wl[(size_t)k * 256 + n];
  dst[i] = f2bf(v);
}

// ===========================================================================
// Affine GEMM (proven): xb[M,256] = bf16(fb[M,128] @ Wta^T + bias)
// ===========================================================================
__global__ __launch_bounds__(256) void mfma_gemm_kernel(
    const unsigned short* __restrict__ A, const unsigned short* __restrict__ Bt,
    const float* __restrict__ bias, unsigned short* __restrict__ C, int M,
    int K) {
  __shared__ __align__(16) unsigned short As[128 * 64];
  __shared__ __align__(16) unsigned short Bs[128 * 64];

  const int tid = threadIdx.x;
  const int lane = tid & 63;
  const int wave = tid >> 6;
  const int bm = blockIdx.y * 128;
  const int bn = blockIdx.x * 128;
  const int wr = wave >> 1;
  const int wc = wave & 1;

  f32x4 acc[4][4];
#pragma unroll
  for (int i = 0; i < 4; ++i)
#pragma unroll
    for (int j = 0; j < 4; ++j) acc[i][j] = (f32x4){0.f, 0.f, 0.f, 0.f};

  const int g = lane >> 4;
  const int rl = lane & 15;

  for (int k0 = 0; k0 < K; k0 += 64) {
#pragma unroll
    for (int c = 0; c < 8; ++c) {
      const int chunk = c * 4 + wave;
      if (chunk < 16) {
        const int S = chunk * 64 + lane;
        const int row = S >> 3;
        const int s = S & 7;
        int grow = bm + row;
        if (grow > M - 1) grow = M - 1;
        const int kcol = k0 + ((s ^ (row & 7)) << 3);
        const unsigned short* gp = A + (size_t)grow * K + kcol;
        unsigned short* lp = As + (size_t)chunk * 512;
        __builtin_amdgcn_global_load_lds(
            (const __attribute__((address_space(1))) void*)gp,
            (__attribute__((address_space(3))) void*)lp, 16, 0, 0);
      } else {
        const int S = (chunk - 16) * 64 + lane;
        const int row = S >> 3;
        const int s = S & 7;
        const int kcol = k0 + ((s ^ (row & 7)) << 3);
        const unsigned short* gp = Bt + (size_t)(bn + row) * K + kcol;
        unsigned short* lp = Bs + (size_t)(chunk - 16) * 512;
        __builtin_amdgcn_global_load_lds(
            (const __attribute__((address_space(1))) void*)gp,
            (__attribute__((address_space(3))) void*)lp, 16, 0, 0);
      }
    }
    __syncthreads();

#pragma unroll
    for (int kk = 0; kk < 2; ++kk) {
      short8 a[4], b[4];
#pragma unroll
      for (int mi = 0; mi < 4; ++mi) {
        const int row = wr * 64 + mi * 16 + rl;
        const int slot = (kk * 4 + g) ^ (row & 7);
        a[mi] = *(const short8*)&As[row * 64 + slot * 8];
      }
#pragma unroll
      for (int ni = 0; ni < 4; ++ni) {
        const int row = wc * 64 + ni * 16 + rl;
        const int slot = (kk * 4 + g) ^ (row & 7);
        b[ni] = *(const short8*)&Bs[row * 64 + slot * 8];
      }
#pragma unroll
      for (int mi = 0; mi < 4; ++mi)
#pragma unroll
        for (int ni = 0; ni < 4; ++ni)
          acc[mi][ni] = __builtin_amdgcn_mfma_f32_16x16x32_bf16(
              a[mi], b[ni], acc[mi][ni], 0, 0, 0);
    }
    __syncthreads();
  }

#pragma unroll
  for (int mi = 0; mi < 4; ++mi) {
#pragma unroll
    for (int j = 0; j < 4; ++j) {
      const int row = bm + wr * 64 + mi * 16 + g * 4 + j;
      if (row >= M) continue;
#pragma unroll
      for (int ni = 0; ni < 4; ++ni) {
        const int col = bn + wc * 64 + ni * 16 + rl;
        C[(size_t)row * DDIM + col] = f2bf(acc[mi][ni][j] + bias[col]);
      }
    }
  }
}

// ===========================================================================
// Fused R-GCN: per block of 64 nodes, 17 phases (8 fwd, 8 bwd, selfloop):
//   phase p: zero Zacc -> gather-sum x rows into Zacc (fp32 LDS, ds_add,
//   granule XOR swizzle) -> 8 MFMA k-steps with W fragments preloaded into
//   registers from Wcat (per-lane fragment order). Epilogue writes h (fp32)
//   and hbf (bf16) once.
// 256 threads = 4 waves; wave w owns cols [w*64, w*64+64); 64 KB LDS ->
// 2 blocks/CU so gather of one block overlaps MFMA of the other.
// ===========================================================================
__global__ __launch_bounds__(256, 2) void fused_rgcn_kernel(
    const unsigned short* __restrict__ xb, const unsigned short* __restrict__ Wcat,
    const int* __restrict__ offs, const int2* __restrict__ pairs,
    float* __restrict__ h, unsigned short* __restrict__ hbf) {
  __shared__ float Zacc[64 * 256];  // [row][256 fp32], 16B-granule swizzled

  const int tid = threadIdx.x;
  const int lane = tid & 63;
  const int w = tid >> 6;
  const int bm = blockIdx.x * 64;
  const int g = lane >> 4;
  const int rl = lane & 15;

  f32x4 acc[4][4];
#pragma unroll
  for (int i = 0; i < 4; ++i)
#pragma unroll
    for (int j = 0; j < 4; ++j) acc[i][j] = (f32x4){0.f, 0.f, 0.f, 0.f};

#pragma unroll 1
  for (int p = 0; p < NPHASE; ++p) {
    // ---- preload this phase's B fragments (latency hidden by zero+gather)
    short8 breg[8][4];
#pragma unroll
    for (int t = 0; t < 8; ++t)
#pragma unroll
      for (int ni = 0; ni < 4; ++ni)
        breg[t][ni] = *(const short8*)&Wcat[(size_t)((((p * 8 + t) * 4 + w) * 4 + ni) * 512) + lane * 8];

    __syncthreads();  // previous phase's MFMA reads done

    if (p < 16) {
      // ---- zero Zacc
#pragma unroll
      for (int z = 0; z < 16; ++z)
        *(f32x4*)&Zacc[z * 1024 + tid * 4] = (f32x4){0.f, 0.f, 0.f, 0.f};
      __syncthreads();

      // ---- gather: contiguous span of this block's 64 buckets in phase p
      const int vend = (bm + 64 < N_NODES) ? bm + 64 : N_NODES;
      const int s0 = offs[p * N_NODES + bm];
      const int e0 = offs[p * N_NODES + vend];
      for (int base = s0 + w; base < e0; base += 32) {  // 8-deep batches
        int2 prs[8];
        ushort4 xs[8];
#pragma unroll
        for (int q = 0; q < 8; ++q) {
          const int i = base + q * 4;
          if (i < e0) prs[q] = pairs[i];
        }
#pragma unroll
        for (int q = 0; q < 8; ++q) {
          const int i = base + q * 4;
          if (i < e0)
            xs[q] = *(const ushort4*)&xb[(size_t)prs[q].x * 256 + lane * 4];
        }
#pragma unroll
        for (int q = 0; q < 8; ++q) {
          const int i = base + q * 4;
          if (i < e0) {
            const int row = prs[q].y - bm;
            float* zp = &Zacc[row * 256 + ((lane ^ (row & 7)) << 2)];
            atomicAdd(zp + 0, bf2f(xs[q].x));
            atomicAdd(zp + 1, bf2f(xs[q].y));
            atomicAdd(zp + 2, bf2f(xs[q].z));
            atomicAdd(zp + 3, bf2f(xs[q].w));
          }
        }
      }
    } else {
      // ---- self-loop: Zacc[row] = fp32(xb[bm+row]) (full overwrite)
#pragma unroll
      for (int it = 0; it < 16; ++it) {
        const int row = w * 16 + it;
        int gr = bm + row;
        if (gr > N_NODES - 1) gr = N_NODES - 1;
        const ushort4 t4 = *(const ushort4*)&xb[(size_t)gr * 256 + lane * 4];
        f32x4 f4 = {bf2f(t4.x), bf2f(t4.y), bf2f(t4.z), bf2f(t4.w)};
        *(f32x4*)&Zacc[row * 256 + ((lane ^ (row & 7)) << 2)] = f4;
      }
    }
    __syncthreads();

    // ---- 8 MFMA k-steps (K=256), B from registers, A from swizzled Zacc
#pragma unroll
    for (int t = 0; t < 8; ++t) {
      short8 a[4];
#pragma unroll
      for (int mi = 0; mi < 4; ++mi) {
        const int row = mi * 16 + rl;
        const int sw = row & 7;
        const int kg = t * 8 + g * 2;
        const f32x4 lo = *(const f32x4*)&Zacc[row * 256 + ((kg ^ sw) << 2)];
        const f32x4 hi = *(const f32x4*)&Zacc[row * 256 + (((kg + 1) ^ sw) << 2)];
        a[mi] = cvt8(lo, hi);
      }
#pragma unroll
      for (int mi = 0; mi < 4; ++mi)
#pragma unroll
        for (int ni = 0; ni < 4; ++ni)
          acc[mi][ni] = __builtin_amdgcn_mfma_f32_16x16x32_bf16(
              a[mi], breg[t][ni], acc[mi][ni], 0, 0, 0);
    }
  }

  // ---- epilogue: h fp32 + hbf bf16, written once
#pragma unroll
  for (int mi = 0; mi < 4; ++mi) {
#pragma unroll
    for (int j = 0; j < 4; ++j) {
      const int row = bm + mi * 16 + g * 4 + j;
      if (row >= N_NODES) continue;
#pragma unroll
      for (int ni = 0; ni < 4; ++ni) {
        const int col = w * 64 + ni * 16 + rl;
        const float v = acc[mi][ni][j];
        h[(size_t)row * DDIM + col] = v;
        hbf[(size_t)row * DDIM + col] = f2bf(v);
      }
    }
  }
}

// ===========================================================================
// DistMult scoring from bf16 h copy.
// ===========================================================================
__global__ __launch_bounds__(256) void score_bf16_kernel(
    const unsigned short* __restrict__ hb, const float* __restrict__ wrel,
    const int* __restrict__ ts, const int* __restrict__ tr,
    const int* __restrict__ to, float* __restrict__ out, int T) {
  const int t = blockIdx.x * 4 + (threadIdx.x >> 6);
  if (t >= T) return;
  const int lane = threadIdx.x & 63;
  const int s = ts[t];
  const int r = tr[t];
  const int o = to[t];
  const ushort4 hs =
      *reinterpret_cast<const ushort4*>(&hb[(size_t)s * DDIM + lane * 4]);
  const ushort4 ho =
      *reinterpret_cast<const ushort4*>(&hb[(size_t)o * DDIM + lane * 4]);
  const float4 wr =
      *reinterpret_cast<const float4*>(&wrel[(size_t)r * DDIM + lane * 4]);
  float sum = bf2f(hs.x) * wr.x * bf2f(ho.x) + bf2f(hs.y) * wr.y * bf2f(ho.y) +
              bf2f(hs.z) * wr.z * bf2f(ho.z) + bf2f(hs.w) * wr.w * bf2f(ho.w);
#pragma unroll
  for (int off = 32; off; off >>= 1) sum += __shfl_down(sum, off, 64);
  if (lane == 0) out[t] = sum;
}

// ===========================================================================
extern "C" void kernel_launch(void* const* d_in, const int* in_sizes, int n_in,
                              void* d_out, int out_size, void* d_ws,
                              size_t ws_size, hipStream_t stream) {
  const float* feats = (const float*)d_in[0];
  const float* W_affine = (const float*)d_in[1];
  const float* b_affine = (const float*)d_in[2];
  const float* W_fwd = (const float*)d_in[3];
  const float* W_bwd = (const float*)d_in[4];
  const float* W_loop = (const float*)d_in[5];
  const float* w_relation = (const float*)d_in[6];
  const int* src = (const int*)d_in[7];
  const int* dst = (const int*)d_in[8];
  const int* etype = (const int*)d_in[9];
  const int* trip_s = (const int*)d_in[10];
  const int* trip_r = (const int*)d_in[11];
  const int* trip_o = (const int*)d_in[12];

  float* out_w = (float*)d_out;  // [N_TRIP]
  float* h = out_w + N_TRIP;     // [N_NODES * D] fp32

  char* ws = (char*)d_ws;
  unsigned short* fb = (unsigned short*)(ws);               // 7,680,000
  unsigned short* xb = (unsigned short*)(ws + 7680000);     // 15,360,000
  unsigned short* hbf = (unsigned short*)(ws + 23040000);   // 15,360,000
  unsigned short* Wta = (unsigned short*)(ws + 38400000);   // 65,536
  unsigned short* Wcat = (unsigned short*)(ws + 38465536);  // 2,228,224
  int* cnt = (int*)(ws + 40693760);                         // 1,921,024
  int* offs = (int*)(ws + 42614784);                        // 1,921,024
  int* cur = (int*)(ws + 44535808);                         // 1,921,024
  int* bsum = (int*)(ws + 46456832);                        // 2,048
  int2* pairs = (int2*)(ws + 46458880);                     // 4,800,000

  // ---- edge bucketing ----
  zero_int_kernel<<<(NPAD + 255) / 256, 256, 0, stream>>>(cnt, NPAD);
  hist_kernel<<<(N_EDGES + 255) / 256, 256, 0, stream>>>(src, dst, etype, cnt);
  scan1_kernel<<<NCHUNK, 256, 0, stream>>>(cnt, offs, bsum);
  scan2_kernel<<<1, 512, 0, stream>>>(bsum);
  scan3_kernel<<<(NPAD + 255) / 256, 256, 0, stream>>>(offs, bsum, cur);
  fill_kernel<<<(N_EDGES + 255) / 256, 256, 0, stream>>>(src, dst, etype, cur,
                                                         pairs);

  // ---- conversions / weight prep ----
  convert_bf16_kernel<<<(N_NODES * F_RAW + 255) / 256, 256, 0, stream>>>(
      feats, fb, N_NODES * F_RAW);
  transpose_bf16_kernel<<<(F_RAW * DDIM + 255) / 256, 256, 0, stream>>>(
      W_affine, Wta, 1, F_RAW, DDIM);
  build_wcat_kernel<<<(WCAT_ELEMS + 255) / 256, 256, 0, stream>>>(
      W_fwd, W_bwd, W_loop, Wcat);

  // ---- xb = bf16(feats @ W_affine + b) ----
  const dim3 agrid(DDIM / 128, (N_NODES + 127) / 128);
  mfma_gemm_kernel<<<agrid, 256, 0, stream>>>(fb, Wta, b_affine, xb, N_NODES,
                                              F_RAW);

  // ---- fused gather + 17-phase MFMA -> h, hbf ----
  fused_rgcn_kernel<<<(N_NODES + 63) / 64, 256, 0, stream>>>(xb, Wcat, offs,
                                                             pairs, h, hbf);

  // ---- DistMult scoring ----
  score_bf16_kernel<<<(N_TRIP + 3) / 4, 256, 0, stream>>>(
      hbf, w_relation, trip_s, trip_r, trip_o, out_w, N_TRIP);
}

// Round 6
// 359.919 us; speedup vs baseline: 3.1814x; 3.1814x over previous
//
#include <hip/hip_runtime.h>

#define N_NODES 30000
#define N_EDGES 300000
#define N_TRIP 200000
#define NUM_RELS 8
#define F_RAW 128
#define DDIM 256

#define NBUCK (2 * NUM_RELS * N_NODES)                    // 480000 buckets
#define SCAN_CHUNK 1024
#define NCHUNK ((NBUCK + SCAN_CHUNK - 1) / SCAN_CHUNK)    // 469
#define NPAD (NCHUNK * SCAN_CHUNK)                        // 480256

#define KBIG 2304   // fallback: 8 rel blocks + x block
#define KBWD 2048
#define KMRG 4352   // merged: 8 fwd + 8 bwd + x

typedef __attribute__((ext_vector_type(8))) short short8;
typedef __attribute__((ext_vector_type(4))) float f32x4;

__device__ inline unsigned short f2bf(float f) {
  unsigned u = __builtin_bit_cast(unsigned, f);
  u = (u + 0x7FFFu + ((u >> 16) & 1u)) >> 16;
  return (unsigned short)u;
}
__device__ inline float bf2f(unsigned short s) {
  unsigned u = ((unsigned)s) << 16;
  return __builtin_bit_cast(float, u);
}

// ===========================================================================
// Edge bucketing: counting sort by (rel, endpoint), both directions.
// fwd key = r*N + dst; bwd key = (8+r)*N + src. gidx[pos] = gather-node.
// ===========================================================================
__global__ void zero_int_kernel(int* __restrict__ p, int n) {
  int i = blockIdx.x * blockDim.x + threadIdx.x;
  if (i < n) p[i] = 0;
}

__global__ void hist_kernel(const int* __restrict__ src,
                            const int* __restrict__ dst,
                            const int* __restrict__ et, int* __restrict__ cnt) {
  int e = blockIdx.x * blockDim.x + threadIdx.x;
  if (e >= N_EDGES) return;
  int r = et[e];
  atomicAdd(&cnt[r * N_NODES + dst[e]], 1);
  atomicAdd(&cnt[(NUM_RELS + r) * N_NODES + src[e]], 1);
}

__global__ __launch_bounds__(256) void scan1_kernel(const int* __restrict__ cnt,
                                                    int* __restrict__ offs,
                                                    int* __restrict__ bsum) {
  __shared__ int s[256];
  const int b = blockIdx.x, t = threadIdx.x;
  const int base = b * SCAN_CHUNK + t * 4;
  int4 v = *reinterpret_cast<const int4*>(&cnt[base]);
  int tsum = v.x + v.y + v.z + v.w;
  s[t] = tsum;
  __syncthreads();
  for (int off = 1; off < 256; off <<= 1) {
    int x = (t >= off) ? s[t - off] : 0;
    __syncthreads();
    s[t] += x;
    __syncthreads();
  }
  int excl = s[t] - tsum;
  offs[base + 0] = excl;
  offs[base + 1] = excl + v.x;
  offs[base + 2] = excl + v.x + v.y;
  offs[base + 3] = excl + v.x + v.y + v.z;
  if (t == 0) bsum[b] = s[255];
}

__global__ __launch_bounds__(512) void scan2_kernel(int* __restrict__ bsum) {
  __shared__ int s[512];
  const int t = threadIdx.x;
  int v = (t < NCHUNK) ? bsum[t] : 0;
  s[t] = v;
  __syncthreads();
  for (int off = 1; off < 512; off <<= 1) {
    int x = (t >= off) ? s[t - off] : 0;
    __syncthreads();
    s[t] += x;
    __syncthreads();
  }
  if (t < NCHUNK) bsum[t] = s[t] - v;
}

__global__ void scan3_kernel(int* __restrict__ offs,
                             const int* __restrict__ bsum,
                             int* __restrict__ cur) {
  int i = blockIdx.x * blockDim.x + threadIdx.x;
  if (i >= NPAD) return;
  int v = offs[i] + bsum[i / SCAN_CHUNK];
  offs[i] = v;
  if (i < NBUCK) cur[i] = v;
}

__global__ void fill_kernel(const int* __restrict__ src,
                            const int* __restrict__ dst,
                            const int* __restrict__ et, int* __restrict__ cur,
                            int* __restrict__ gidx) {
  int e = blockIdx.x * blockDim.x + threadIdx.x;
  if (e >= N_EDGES) return;
  int r = et[e];
  int s = src[e], d = dst[e];
  int p1 = atomicAdd(&cur[r * N_NODES + d], 1);
  gidx[p1] = s;  // fwd: gather src, owner dst
  int p2 = atomicAdd(&cur[(NUM_RELS + r) * N_NODES + s], 1);
  gidx[p2] = d;  // bwd: gather dst, owner src
}

// ===========================================================================
// Conversions / weight prep
// ===========================================================================
__global__ void convert_bf16_kernel(const float* __restrict__ src,
                                    unsigned short* __restrict__ dst,
                                    int total) {
  const int i = blockIdx.x * blockDim.x + threadIdx.x;
  if (i < total) dst[i] = f2bf(src[i]);
}

__global__ void transpose_bf16_kernel(const float* __restrict__ src,
                                      unsigned short* __restrict__ dst,
                                      int R, int K, int N) {
  const int i = blockIdx.x * blockDim.x + threadIdx.x;
  const int total = R * K * N;
  if (i >= total) return;
  const int r = i / (K * N);
  const int rem = i - r * K * N;
  const int k = rem / N;
  const int n = rem - k * N;
  dst[(size_t)r * K * N + (size_t)n * K + k] = f2bf(src[i]);
}

// Fallback: Wcat [256][KK]; kk<2048 from W8[kk>>8][kk&255][n], else Wextra.
__global__ void build_wcat2_kernel(const float* __restrict__ W8,
                                   const float* __restrict__ Wextra,
                                   unsigned short* __restrict__ dst, int KK) {
  const int i = blockIdx.x * blockDim.x + threadIdx.x;
  if (i >= 256 * KK) return;
  const int n = i / KK;
  const int kk = i - n * KK;
  float v;
  if (kk < 2048) {
    const int r = kk >> 8, k = kk & 255;
    v = W8[((size_t)r * 256 + k) * 256 + n];
  } else {
    v = Wextra[(size_t)(kk - 2048) * 256 + n];
  }
  dst[i] = f2bf(v);
}

// Merged: Wcat [256][4352]; [0,2048)=Wf, [2048,4096)=Wb, [4096,4352)=Wl.
__global__ void build_wcat3_kernel(const float* __restrict__ Wf,
                                   const float* __restrict__ Wb,
                                   const float* __restrict__ Wl,
                                   unsigned short* __restrict__ dst) {
  const int i = blockIdx.x * blockDim.x + threadIdx.x;
  if (i >= 256 * KMRG) return;
  const int n = i / KMRG;
  const int kk = i - n * KMRG;
  float v;
  if (kk < 2048) {
    const int r = kk >> 8, k = kk & 255;
    v = Wf[((size_t)r * 256 + k) * 256 + n];
  } else if (kk < 4096) {
    const int r = (kk - 2048) >> 8, k = kk & 255;
    v = Wb[((size_t)r * 256 + k) * 256 + n];
  } else {
    v = Wl[(size_t)(kk - 4096) * 256 + n];
  }
  dst[i] = f2bf(v);
}

// ===========================================================================
// bf16 MFMA GEMM (proven 128x128 shape): C[M, bn..] = A[M,K] @ Bt[bn..][K]^T
// 256 threads = 4 waves (2x2 quadrants of 64x64), BK=64, gload_lds staging
// with XOR-swizzled global source + matching swizzled ds_read.
// OUT_MODE: 0 f32; 1 bf16; 2 f32-RMW + bf16; 3 f32 + bf16.
// ===========================================================================
template <int OUT_MODE, int ADD_BIAS>
__global__ __launch_bounds__(256) void gemm128_kernel(
    const unsigned short* __restrict__ A, int lda, int K,
    const unsigned short* __restrict__ Bt, const float* __restrict__ bias,
    float* __restrict__ Cf, unsigned short* __restrict__ Cb, int ldc, int M) {
  __shared__ __align__(16) unsigned short As[128 * 64];
  __shared__ __align__(16) unsigned short Bs[128 * 64];

  const int tid = threadIdx.x;
  const int lane = tid & 63;
  const int wave = tid >> 6;
  const int bm = blockIdx.y * 128;
  const int bn = blockIdx.x * 128;
  const int wr = wave >> 1;
  const int wc = wave & 1;
  const int g = lane >> 4;
  const int rl = lane & 15;

  f32x4 acc[4][4];
#pragma unroll
  for (int i = 0; i < 4; ++i)
#pragma unroll
    for (int j = 0; j < 4; ++j) acc[i][j] = (f32x4){0.f, 0.f, 0.f, 0.f};

  for (int k0 = 0; k0 < K; k0 += 64) {
#pragma unroll
    for (int c = 0; c < 8; ++c) {
      const int chunk = c * 4 + wave;
      if (chunk < 16) {
        const int S = chunk * 64 + lane;
        const int row = S >> 3;
        const int s = S & 7;
        int grow = bm + row;
        if (grow > M - 1) grow = M - 1;
        const int kcol = k0 + ((s ^ (row & 7)) << 3);
        const unsigned short* gp = A + (size_t)grow * lda + kcol;
        unsigned short* lp = As + (size_t)chunk * 512;
        __builtin_amdgcn_global_load_lds(
            (const __attribute__((address_space(1))) void*)gp,
            (__attribute__((address_space(3))) void*)lp, 16, 0, 0);
      } else {
        const int S = (chunk - 16) * 64 + lane;
        const int row = S >> 3;
        const int s = S & 7;
        const int kcol = k0 + ((s ^ (row & 7)) << 3);
        const unsigned short* gp = Bt + (size_t)(bn + row) * K + kcol;
        unsigned short* lp = Bs + (size_t)(chunk - 16) * 512;
        __builtin_amdgcn_global_load_lds(
            (const __attribute__((address_space(1))) void*)gp,
            (__attribute__((address_space(3))) void*)lp, 16, 0, 0);
      }
    }
    __syncthreads();

#pragma unroll
    for (int kk = 0; kk < 2; ++kk) {
      short8 a[4], b[4];
#pragma unroll
      for (int mi = 0; mi < 4; ++mi) {
        const int row = wr * 64 + mi * 16 + rl;
        const int slot = (kk * 4 + g) ^ (row & 7);
        a[mi] = *(const short8*)&As[row * 64 + slot * 8];
      }
#pragma unroll
      for (int ni = 0; ni < 4; ++ni) {
        const int row = wc * 64 + ni * 16 + rl;
        const int slot = (kk * 4 + g) ^ (row & 7);
        b[ni] = *(const short8*)&Bs[row * 64 + slot * 8];
      }
#pragma unroll
      for (int mi = 0; mi < 4; ++mi)
#pragma unroll
        for (int ni = 0; ni < 4; ++ni)
          acc[mi][ni] = __builtin_amdgcn_mfma_f32_16x16x32_bf16(
              a[mi], b[ni], acc[mi][ni], 0, 0, 0);
    }
    __syncthreads();
  }

#pragma unroll
  for (int mi = 0; mi < 4; ++mi) {
#pragma unroll
    for (int j = 0; j < 4; ++j) {
      const int row = bm + wr * 64 + mi * 16 + g * 4 + j;
      if (row >= M) continue;
#pragma unroll
      for (int ni = 0; ni < 4; ++ni) {
        const int col = bn + wc * 64 + ni * 16 + rl;
        float v = acc[mi][ni][j];
        if (ADD_BIAS) v += bias[col];
        const size_t idx = (size_t)row * ldc + col;
        if (OUT_MODE == 0) {
          Cf[idx] = v;
        } else if (OUT_MODE == 1) {
          Cb[idx] = f2bf(v);
        } else if (OUT_MODE == 2) {
          v += Cf[idx];
          Cf[idx] = v;
          Cb[idx] = f2bf(v);
        } else {
          Cf[idx] = v;
          Cb[idx] = f2bf(v);
        }
      }
    }
  }
}

// ===========================================================================
// z-gather: one wave per bucket (r,v). Z[v, colbase + r*256 + :] =
// sum over bucket of x rows (x tail at col xoff). gidx gives gather node
// directly (no indirection); 4-deep load batching.
// ===========================================================================
__global__ __launch_bounds__(256) void zgather_kernel(
    unsigned short* __restrict__ Z, int ldz, int colbase, int xoff,
    const int* __restrict__ offs_base, const int* __restrict__ gidx) {
  const int b = blockIdx.x * 4 + (threadIdx.x >> 6);
  if (b >= NUM_RELS * N_NODES) return;
  const int lane = threadIdx.x & 63;
  const int r = b / N_NODES;
  const int v = b - r * N_NODES;
  const int s = offs_base[b], e = offs_base[b + 1];

  float ax = 0.f, ay = 0.f, az = 0.f, aw = 0.f;
  for (int i = s; i < e; i += 4) {
    int gq[4];
    ushort4 xs[4];
#pragma unroll
    for (int q = 0; q < 4; ++q)
      if (i + q < e) gq[q] = gidx[i + q];
#pragma unroll
    for (int q = 0; q < 4; ++q)
      if (i + q < e)
        xs[q] = *(const ushort4*)&Z[(size_t)gq[q] * ldz + xoff + lane * 4];
#pragma unroll
    for (int q = 0; q < 4; ++q)
      if (i + q < e) {
        ax += bf2f(xs[q].x);
        ay += bf2f(xs[q].y);
        az += bf2f(xs[q].z);
        aw += bf2f(xs[q].w);
      }
  }
  ushort4 o;
  o.x = f2bf(ax); o.y = f2bf(ay); o.z = f2bf(az); o.w = f2bf(aw);
  *(ushort4*)&Z[(size_t)v * ldz + colbase + r * 256 + lane * 4] = o;
}

// ===========================================================================
// DistMult scoring from bf16 h copy.
// ===========================================================================
__global__ __launch_bounds__(256) void score_bf16_kernel(
    const unsigned short* __restrict__ hb, const float* __restrict__ wrel,
    const int* __restrict__ ts, const int* __restrict__ tr,
    const int* __restrict__ to, float* __restrict__ out, int T) {
  const int t = blockIdx.x * 4 + (threadIdx.x >> 6);
  if (t >= T) return;
  const int lane = threadIdx.x & 63;
  const int s = ts[t];
  const int r = tr[t];
  const int o = to[t];
  const ushort4 hs =
      *reinterpret_cast<const ushort4*>(&hb[(size_t)s * DDIM + lane * 4]);
  const ushort4 ho =
      *reinterpret_cast<const ushort4*>(&hb[(size_t)o * DDIM + lane * 4]);
  const float4 wr =
      *reinterpret_cast<const float4*>(&wrel[(size_t)r * DDIM + lane * 4]);
  float sum = bf2f(hs.x) * wr.x * bf2f(ho.x) + bf2f(hs.y) * wr.y * bf2f(ho.y) +
              bf2f(hs.z) * wr.z * bf2f(ho.z) + bf2f(hs.w) * wr.w * bf2f(ho.w);
#pragma unroll
  for (int off = 32; off; off >>= 1) sum += __shfl_down(sum, off, 64);
  if (lane == 0) out[t] = sum;
}

// ===========================================================================
extern "C" void kernel_launch(void* const* d_in, const int* in_sizes, int n_in,
                              void* d_out, int out_size, void* d_ws,
                              size_t ws_size, hipStream_t stream) {
  const float* feats = (const float*)d_in[0];
  const float* W_affine = (const float*)d_in[1];
  const float* b_affine = (const float*)d_in[2];
  const float* W_fwd = (const float*)d_in[3];
  const float* W_bwd = (const float*)d_in[4];
  const float* W_loop = (const float*)d_in[5];
  const float* w_relation = (const float*)d_in[6];
  const int* src = (const int*)d_in[7];
  const int* dst = (const int*)d_in[8];
  const int* etype = (const int*)d_in[9];
  const int* trip_s = (const int*)d_in[10];
  const int* trip_r = (const int*)d_in[11];
  const int* trip_o = (const int*)d_in[12];

  float* out_w = (float*)d_out;  // [N_TRIP]
  float* h = out_w + N_TRIP;     // [N_NODES * D] fp32

  char* ws = (char*)d_ws;
  const dim3 ggrid(2, (N_NODES + 127) / 128);  // N=256 GEMMs: 470 blocks

  if (ws_size >= 295000000ULL) {
    // ------------------- MERGED PATH (K=4352, one wide GEMM) -------------------
    unsigned short* fb = (unsigned short*)(ws);                 // 7,680,000
    unsigned short* Z = (unsigned short*)(ws + 7680000);        // 261,120,000
    unsigned short* hbf = (unsigned short*)(ws + 268800000);    // 15,360,000
    unsigned short* Wta = (unsigned short*)(ws + 284160000);    // 65,536
    unsigned short* Wcat = (unsigned short*)(ws + 284225536);   // 2,228,224
    int* cnt = (int*)(ws + 286453760);                          // 1,921,024
    int* offs = (int*)(ws + 288374784);                         // 1,921,024
    int* cur = (int*)(ws + 290295808);                          // 1,921,024
    int* bsum = (int*)(ws + 292216832);                         // 2,048
    int* gidx = (int*)(ws + 292218880);                         // 2,400,000

    zero_int_kernel<<<(NPAD + 255) / 256, 256, 0, stream>>>(cnt, NPAD);
    hist_kernel<<<(N_EDGES + 255) / 256, 256, 0, stream>>>(src, dst, etype, cnt);
    scan1_kernel<<<NCHUNK, 256, 0, stream>>>(cnt, offs, bsum);
    scan2_kernel<<<1, 512, 0, stream>>>(bsum);
    scan3_kernel<<<(NPAD + 255) / 256, 256, 0, stream>>>(offs, bsum, cur);
    fill_kernel<<<(N_EDGES + 255) / 256, 256, 0, stream>>>(src, dst, etype,
                                                           cur, gidx);

    convert_bf16_kernel<<<(N_NODES * F_RAW + 255) / 256, 256, 0, stream>>>(
        feats, fb, N_NODES * F_RAW);
    transpose_bf16_kernel<<<(F_RAW * DDIM + 255) / 256, 256, 0, stream>>>(
        W_affine, Wta, 1, F_RAW, DDIM);
    build_wcat3_kernel<<<(256 * KMRG + 255) / 256, 256, 0, stream>>>(
        W_fwd, W_bwd, W_loop, Wcat);

    // x -> Z cols [4096, 4352)
    gemm128_kernel<1, 1><<<ggrid, 256, 0, stream>>>(
        fb, F_RAW, F_RAW, Wta, b_affine, nullptr, Z + 4096, KMRG, N_NODES);
    // Z_fwd cols [0,2048), Z_bwd cols [2048,4096)
    zgather_kernel<<<(NUM_RELS * N_NODES + 3) / 4, 256, 0, stream>>>(
        Z, KMRG, 0, 4096, offs, gidx);
    zgather_kernel<<<(NUM_RELS * N_NODES + 3) / 4, 256, 0, stream>>>(
        Z, KMRG, 2048, 4096, offs + NUM_RELS * N_NODES, gidx);
    // h(+hbf) = [Z_fwd | Z_bwd | x] @ [Wf ; Wb ; Wl]
    gemm128_kernel<3, 0><<<ggrid, 256, 0, stream>>>(
        Z, KMRG, KMRG, Wcat, nullptr, h, hbf, DDIM, N_NODES);

    score_bf16_kernel<<<(N_TRIP + 3) / 4, 256, 0, stream>>>(
        hbf, w_relation, trip_s, trip_r, trip_o, out_w, N_TRIP);
    return;
  }

  // ------------------- FALLBACK PATH (K=2304 + K=2048, fits 172 MB) ---------
  unsigned short* fb = (unsigned short*)(ws);                 // 7,680,000
  unsigned short* Z = (unsigned short*)(ws + 7680000);        // 138,240,000
  unsigned short* hbf = (unsigned short*)(ws + 145920000);    // 15,360,000
  unsigned short* Wta = (unsigned short*)(ws + 161280000);    // 65,536
  unsigned short* Wcat1 = (unsigned short*)(ws + 161345536);  // 1,179,648
  unsigned short* Wcat2 = (unsigned short*)(ws + 162525184);  // 1,048,576
  int* cnt = (int*)(ws + 163573760);                          // 1,921,024
  int* offs = (int*)(ws + 165494784);                         // 1,921,024
  int* cur = (int*)(ws + 167415808);                          // 1,921,024
  int* bsum = (int*)(ws + 169336832);                         // 2,048
  int* gidx = (int*)(ws + 169338880);                         // 2,400,000

  zero_int_kernel<<<(NPAD + 255) / 256, 256, 0, stream>>>(cnt, NPAD);
  hist_kernel<<<(N_EDGES + 255) / 256, 256, 0, stream>>>(src, dst, etype, cnt);
  scan1_kernel<<<NCHUNK, 256, 0, stream>>>(cnt, offs, bsum);
  scan2_kernel<<<1, 512, 0, stream>>>(bsum);
  scan3_kernel<<<(NPAD + 255) / 256, 256, 0, stream>>>(offs, bsum, cur);
  fill_kernel<<<(N_EDGES + 255) / 256, 256, 0, stream>>>(src, dst, etype, cur,
                                                         gidx);

  convert_bf16_kernel<<<(N_NODES * F_RAW + 255) / 256, 256, 0, stream>>>(
      feats, fb, N_NODES * F_RAW);
  transpose_bf16_kernel<<<(F_RAW * DDIM + 255) / 256, 256, 0, stream>>>(
      W_affine, Wta, 1, F_RAW, DDIM);
  build_wcat2_kernel<<<(256 * KBIG + 255) / 256, 256, 0, stream>>>(
      W_fwd, W_loop, Wcat1, KBIG);
  build_wcat2_kernel<<<(256 * KBWD + 255) / 256, 256, 0, stream>>>(
      W_bwd, nullptr, Wcat2, KBWD);

  // x -> Z cols [2048, 2304)
  gemm128_kernel<1, 1><<<ggrid, 256, 0, stream>>>(
      fb, F_RAW, F_RAW, Wta, b_affine, nullptr, Z + 2048, KBIG, N_NODES);
  // Z_fwd cols [0,2048); h = [Z_fwd | x] @ [Wf ; Wl]
  zgather_kernel<<<(NUM_RELS * N_NODES + 3) / 4, 256, 0, stream>>>(
      Z, KBIG, 0, 2048, offs, gidx);
  gemm128_kernel<0, 0><<<ggrid, 256, 0, stream>>>(
      Z, KBIG, KBIG, Wcat1, nullptr, h, nullptr, DDIM, N_NODES);
  // Z_bwd overwrites cols [0,2048); h += Z_bwd @ [Wb], emit hbf
  zgather_kernel<<<(NUM_RELS * N_NODES + 3) / 4, 256, 0, stream>>>(
      Z, KBIG, 0, 2048, offs + NUM_RELS * N_NODES, gidx);
  gemm128_kernel<2, 0><<<ggrid, 256, 0, stream>>>(
      Z, KBIG, KBWD, Wcat2, nullptr, h, hbf, DDIM, N_NODES);

  score_bf16_kernel<<<(N_TRIP + 3) / 4, 256, 0, stream>>>(
      hbf, w_relation, trip_s, trip_r, trip_o, out_w, N_TRIP);
}

// Round 7
// 298.144 us; speedup vs baseline: 3.8406x; 1.2072x over previous
//
#include <hip/hip_runtime.h>

#define N_NODES 30000
#define N_EDGES 300000
#define N_TRIP 200000
#define NUM_RELS 8
#define F_RAW 128
#define DDIM 256

#define NBUCK (2 * NUM_RELS * N_NODES)                    // 480000 buckets
#define SCAN_CHUNK 1024
#define NCHUNK ((NBUCK + SCAN_CHUNK - 1) / SCAN_CHUNK)    // 469
#define NPAD (NCHUNK * SCAN_CHUNK)                        // 480256

#define KBIG 2304   // 8 rel blocks + x block
#define KBWD 2048   // 8 rel blocks

typedef __attribute__((ext_vector_type(8))) short short8;
typedef __attribute__((ext_vector_type(8))) unsigned short u16x8;
typedef __attribute__((ext_vector_type(4))) float f32x4;

__device__ inline unsigned short f2bf(float f) {
  unsigned u = __builtin_bit_cast(unsigned, f);
  u = (u + 0x7FFFu + ((u >> 16) & 1u)) >> 16;
  return (unsigned short)u;
}
__device__ inline float bf2f(unsigned short s) {
  unsigned u = ((unsigned)s) << 16;
  return __builtin_bit_cast(float, u);
}

// ===========================================================================
// Edge bucketing: counting sort by (rel, endpoint), both directions.
// fwd key = r*N + dst; bwd key = (8+r)*N + src. gidx[pos] = gather-node.
// ===========================================================================
__global__ void zero_int_kernel(int* __restrict__ p, int n) {
  int i = blockIdx.x * blockDim.x + threadIdx.x;
  if (i < n) p[i] = 0;
}

__global__ void hist_kernel(const int* __restrict__ src,
                            const int* __restrict__ dst,
                            const int* __restrict__ et, int* __restrict__ cnt) {
  int e = blockIdx.x * blockDim.x + threadIdx.x;
  if (e >= N_EDGES) return;
  int r = et[e];
  atomicAdd(&cnt[r * N_NODES + dst[e]], 1);
  atomicAdd(&cnt[(NUM_RELS + r) * N_NODES + src[e]], 1);
}

__global__ __launch_bounds__(256) void scan1_kernel(const int* __restrict__ cnt,
                                                    int* __restrict__ offs,
                                                    int* __restrict__ bsum) {
  __shared__ int s[256];
  const int b = blockIdx.x, t = threadIdx.x;
  const int base = b * SCAN_CHUNK + t * 4;
  int4 v = *reinterpret_cast<const int4*>(&cnt[base]);
  int tsum = v.x + v.y + v.z + v.w;
  s[t] = tsum;
  __syncthreads();
  for (int off = 1; off < 256; off <<= 1) {
    int x = (t >= off) ? s[t - off] : 0;
    __syncthreads();
    s[t] += x;
    __syncthreads();
  }
  int excl = s[t] - tsum;
  offs[base + 0] = excl;
  offs[base + 1] = excl + v.x;
  offs[base + 2] = excl + v.x + v.y;
  offs[base + 3] = excl + v.x + v.y + v.z;
  if (t == 0) bsum[b] = s[255];
}

__global__ __launch_bounds__(512) void scan2_kernel(int* __restrict__ bsum) {
  __shared__ int s[512];
  const int t = threadIdx.x;
  int v = (t < NCHUNK) ? bsum[t] : 0;
  s[t] = v;
  __syncthreads();
  for (int off = 1; off < 512; off <<= 1) {
    int x = (t >= off) ? s[t - off] : 0;
    __syncthreads();
    s[t] += x;
    __syncthreads();
  }
  if (t < NCHUNK) bsum[t] = s[t] - v;
}

__global__ void scan3_kernel(int* __restrict__ offs,
                             const int* __restrict__ bsum,
                             int* __restrict__ cur) {
  int i = blockIdx.x * blockDim.x + threadIdx.x;
  if (i >= NPAD) return;
  int v = offs[i] + bsum[i / SCAN_CHUNK];
  offs[i] = v;
  if (i < NBUCK) cur[i] = v;
}

__global__ void fill_kernel(const int* __restrict__ src,
                            const int* __restrict__ dst,
                            const int* __restrict__ et, int* __restrict__ cur,
                            int* __restrict__ gidx) {
  int e = blockIdx.x * blockDim.x + threadIdx.x;
  if (e >= N_EDGES) return;
  int r = et[e];
  int s = src[e], d = dst[e];
  int p1 = atomicAdd(&cur[r * N_NODES + d], 1);
  gidx[p1] = s;  // fwd: gather src, owner dst
  int p2 = atomicAdd(&cur[(NUM_RELS + r) * N_NODES + s], 1);
  gidx[p2] = d;  // bwd: gather dst, owner src
}

// ===========================================================================
// Conversions / weight prep
// ===========================================================================
__global__ void convert_bf16_kernel(const float* __restrict__ src,
                                    unsigned short* __restrict__ dst,
                                    int total) {
  const int i = blockIdx.x * blockDim.x + threadIdx.x;
  if (i < total) dst[i] = f2bf(src[i]);
}

__global__ void transpose_bf16_kernel(const float* __restrict__ src,
                                      unsigned short* __restrict__ dst,
                                      int R, int K, int N) {
  const int i = blockIdx.x * blockDim.x + threadIdx.x;
  const int total = R * K * N;
  if (i >= total) return;
  const int r = i / (K * N);
  const int rem = i - r * K * N;
  const int k = rem / N;
  const int n = rem - k * N;
  dst[(size_t)r * K * N + (size_t)n * K + k] = f2bf(src[i]);
}

// Wcat [256][KK]; kk<2048 from W8[kk>>8][kk&255][n], else Wextra[k][n].
__global__ void build_wcat2_kernel(const float* __restrict__ W8,
                                   const float* __restrict__ Wextra,
                                   unsigned short* __restrict__ dst, int KK) {
  const int i = blockIdx.x * blockDim.x + threadIdx.x;
  if (i >= 256 * KK) return;
  const int n = i / KK;
  const int kk = i - n * KK;
  float v;
  if (kk < 2048) {
    const int r = kk >> 8, k = kk & 255;
    v = W8[((size_t)r * 256 + k) * 256 + n];
  } else {
    v = Wextra[(size_t)(kk - 2048) * 256 + n];
  }
  dst[i] = f2bf(v);
}

// ===========================================================================
// Affine GEMM (proven 128x128): C_bf16[M, ldc] = A[M,lda(K)] @ Bt[256,K]^T + b
// ===========================================================================
__global__ __launch_bounds__(256) void gemm128_kernel(
    const unsigned short* __restrict__ A, int lda, int K,
    const unsigned short* __restrict__ Bt, const float* __restrict__ bias,
    unsigned short* __restrict__ Cb, int ldc, int M) {
  __shared__ __align__(16) unsigned short As[128 * 64];
  __shared__ __align__(16) unsigned short Bs[128 * 64];

  const int tid = threadIdx.x;
  const int lane = tid & 63;
  const int wave = tid >> 6;
  const int bm = blockIdx.y * 128;
  const int bn = blockIdx.x * 128;
  const int wr = wave >> 1;
  const int wc = wave & 1;
  const int g = lane >> 4;
  const int rl = lane & 15;

  f32x4 acc[4][4];
#pragma unroll
  for (int i = 0; i < 4; ++i)
#pragma unroll
    for (int j = 0; j < 4; ++j) acc[i][j] = (f32x4){0.f, 0.f, 0.f, 0.f};

  for (int k0 = 0; k0 < K; k0 += 64) {
#pragma unroll
    for (int c = 0; c < 8; ++c) {
      const int chunk = c * 4 + wave;
      if (chunk < 16) {
        const int S = chunk * 64 + lane;
        const int row = S >> 3;
        const int s = S & 7;
        int grow = bm + row;
        if (grow > M - 1) grow = M - 1;
        const int kcol = k0 + ((s ^ (row & 7)) << 3);
        const unsigned short* gp = A + (size_t)grow * lda + kcol;
        unsigned short* lp = As + (size_t)chunk * 512;
        __builtin_amdgcn_global_load_lds(
            (const __attribute__((address_space(1))) void*)gp,
            (__attribute__((address_space(3))) void*)lp, 16, 0, 0);
      } else {
        const int S = (chunk - 16) * 64 + lane;
        const int row = S >> 3;
        const int s = S & 7;
        const int kcol = k0 + ((s ^ (row & 7)) << 3);
        const unsigned short* gp = Bt + (size_t)(bn + row) * K + kcol;
        unsigned short* lp = Bs + (size_t)(chunk - 16) * 512;
        __builtin_amdgcn_global_load_lds(
            (const __attribute__((address_space(1))) void*)gp,
            (__attribute__((address_space(3))) void*)lp, 16, 0, 0);
      }
    }
    __syncthreads();

#pragma unroll
    for (int kk = 0; kk < 2; ++kk) {
      short8 a[4], b[4];
#pragma unroll
      for (int mi = 0; mi < 4; ++mi) {
        const int row = wr * 64 + mi * 16 + rl;
        const int slot = (kk * 4 + g) ^ (row & 7);
        a[mi] = *(const short8*)&As[row * 64 + slot * 8];
      }
#pragma unroll
      for (int ni = 0; ni < 4; ++ni) {
        const int row = wc * 64 + ni * 16 + rl;
        const int slot = (kk * 4 + g) ^ (row & 7);
        b[ni] = *(const short8*)&Bs[row * 64 + slot * 8];
      }
#pragma unroll
      for (int mi = 0; mi < 4; ++mi)
#pragma unroll
        for (int ni = 0; ni < 4; ++ni)
          acc[mi][ni] = __builtin_amdgcn_mfma_f32_16x16x32_bf16(
              a[mi], b[ni], acc[mi][ni], 0, 0, 0);
    }
    __syncthreads();
  }

#pragma unroll
  for (int mi = 0; mi < 4; ++mi) {
#pragma unroll
    for (int j = 0; j < 4; ++j) {
      const int row = bm + wr * 64 + mi * 16 + g * 4 + j;
      if (row >= M) continue;
#pragma unroll
      for (int ni = 0; ni < 4; ++ni) {
        const int col = bn + wc * 64 + ni * 16 + rl;
        Cb[(size_t)row * ldc + col] = f2bf(acc[mi][ni][j] + bias[col]);
      }
    }
  }
}

// ===========================================================================
// Wide-K GEMM, BM=64 x BN=128 (high-TLP variant): 938 blocks, 24 KB LDS,
// bijective XCD swizzle. C[M,256] = A[M,K(lda)] @ Bt[256,K]^T.
// OUT_MODE: 0 = write f32; 2 = f32-RMW + bf16 copy.
// ===========================================================================
template <int OUT_MODE>
__global__ __launch_bounds__(256) void gemm64_kernel(
    const unsigned short* __restrict__ A, int lda, int K,
    const unsigned short* __restrict__ Bt, float* __restrict__ Cf,
    unsigned short* __restrict__ Cb, int ldc, int M, int nblk) {
  __shared__ __align__(16) unsigned short As[64 * 64];   // 8 KB
  __shared__ __align__(16) unsigned short Bs[128 * 64];  // 16 KB

  const int tid = threadIdx.x;
  const int lane = tid & 63;
  const int wave = tid >> 6;

  // bijective XCD swizzle (m204 variant: nblk % 8 != 0 safe)
  const int orig = blockIdx.x;
  const int q = nblk >> 3, r = nblk & 7;
  const int xcd = orig & 7, off = orig >> 3;
  const int wg =
      (xcd < r) ? xcd * (q + 1) + off : r * (q + 1) + (xcd - r) * q + off;
  const int bm = (wg >> 1) * 64;
  const int bn = (wg & 1) * 128;

  const int wr = wave >> 1;  // 0..1: 32-row half
  const int wc = wave & 1;   // 0..1: 64-col half
  const int g = lane >> 4;
  const int rl = lane & 15;

  f32x4 acc[2][4];
#pragma unroll
  for (int i = 0; i < 2; ++i)
#pragma unroll
    for (int j = 0; j < 4; ++j) acc[i][j] = (f32x4){0.f, 0.f, 0.f, 0.f};

  for (int k0 = 0; k0 < K; k0 += 64) {
    // stage A (8 x 1KB) + B (16 x 1KB): 6 chunks per wave
#pragma unroll
    for (int c = 0; c < 6; ++c) {
      const int chunk = c * 4 + wave;
      if (chunk < 8) {
        const int S = chunk * 64 + lane;
        const int row = S >> 3;  // 0..63
        const int s = S & 7;
        int grow = bm + row;
        if (grow > M - 1) grow = M - 1;
        const unsigned short* gp =
            A + (size_t)grow * lda + k0 + ((s ^ (row & 7)) << 3);
        unsigned short* lp = As + (size_t)chunk * 512;
        __builtin_amdgcn_global_load_lds(
            (const __attribute__((address_space(1))) void*)gp,
            (__attribute__((address_space(3))) void*)lp, 16, 0, 0);
      } else {
        const int S = (chunk - 8) * 64 + lane;
        const int row = S >> 3;  // 0..127
        const int s = S & 7;
        const unsigned short* gp =
            Bt + (size_t)(bn + row) * K + k0 + ((s ^ (row & 7)) << 3);
        unsigned short* lp = Bs + (size_t)(chunk - 8) * 512;
        __builtin_amdgcn_global_load_lds(
            (const __attribute__((address_space(1))) void*)gp,
            (__attribute__((address_space(3))) void*)lp, 16, 0, 0);
      }
    }
    __syncthreads();

#pragma unroll
    for (int kk = 0; kk < 2; ++kk) {
      short8 a[2], b[4];
#pragma unroll
      for (int mi = 0; mi < 2; ++mi) {
        const int row = wr * 32 + mi * 16 + rl;
        const int slot = (kk * 4 + g) ^ (row & 7);
        a[mi] = *(const short8*)&As[row * 64 + slot * 8];
      }
#pragma unroll
      for (int ni = 0; ni < 4; ++ni) {
        const int row = wc * 64 + ni * 16 + rl;
        const int slot = (kk * 4 + g) ^ (row & 7);
        b[ni] = *(const short8*)&Bs[row * 64 + slot * 8];
      }
#pragma unroll
      for (int mi = 0; mi < 2; ++mi)
#pragma unroll
        for (int ni = 0; ni < 4; ++ni)
          acc[mi][ni] = __builtin_amdgcn_mfma_f32_16x16x32_bf16(
              a[mi], b[ni], acc[mi][ni], 0, 0, 0);
    }
    __syncthreads();
  }

#pragma unroll
  for (int mi = 0; mi < 2; ++mi) {
#pragma unroll
    for (int j = 0; j < 4; ++j) {
      const int row = bm + wr * 32 + mi * 16 + g * 4 + j;
      if (row >= M) continue;
#pragma unroll
      for (int ni = 0; ni < 4; ++ni) {
        const int col = bn + wc * 64 + ni * 16 + rl;
        float v = acc[mi][ni][j];
        const size_t idx = (size_t)row * ldc + col;
        if (OUT_MODE == 0) {
          Cf[idx] = v;
        } else {
          v += Cf[idx];
          Cf[idx] = v;
          Cb[idx] = f2bf(v);
        }
      }
    }
  }
}

// ===========================================================================
// z-gather (32-lane rows): 2 buckets per wave, 16 B/lane loads, 4-deep batch.
// Z[v, colbase + r*256 + :] = sum over bucket of x rows (x tail at col 2048).
// ===========================================================================
__global__ __launch_bounds__(256) void zgatherw_kernel(
    unsigned short* __restrict__ Z, int colbase,
    const int* __restrict__ offs_base, const int* __restrict__ gidx) {
  const int lane = threadIdx.x & 63;
  const int hl = lane >> 5;
  const int l5 = lane & 31;
  const int b = blockIdx.x * 8 + (threadIdx.x >> 6) * 2 + hl;
  if (b >= NUM_RELS * N_NODES) return;
  const int r = b / N_NODES;
  const int v = b - r * N_NODES;
  const int s = offs_base[b], e = offs_base[b + 1];

  float acc[8] = {};
  for (int i = s; i < e; i += 4) {
    int g4[4];
    u16x8 xs[4];
#pragma unroll
    for (int q = 0; q < 4; ++q)
      if (i + q < e) g4[q] = gidx[i + q];
#pragma unroll
    for (int q = 0; q < 4; ++q)
      if (i + q < e)
        xs[q] = *(const u16x8*)&Z[(size_t)g4[q] * KBIG + 2048 + l5 * 8];
#pragma unroll
    for (int q = 0; q < 4; ++q)
      if (i + q < e) {
#pragma unroll
        for (int j = 0; j < 8; ++j) acc[j] += bf2f((unsigned short)xs[q][j]);
      }
  }
  u16x8 o;
#pragma unroll
  for (int j = 0; j < 8; ++j) o[j] = (short)f2bf(acc[j]);
  *(u16x8*)&Z[(size_t)v * KBIG + colbase + r * 256 + l5 * 8] = o;
}

// ===========================================================================
// DistMult scoring (32-lane rows): 2 triples/wave, ushort8 h loads.
// ===========================================================================
__global__ __launch_bounds__(256) void score32_kernel(
    const unsigned short* __restrict__ hb, const float* __restrict__ wrel,
    const int* __restrict__ ts, const int* __restrict__ tr,
    const int* __restrict__ to, float* __restrict__ out, int T) {
  const int t = blockIdx.x * 8 + (threadIdx.x >> 5);
  if (t >= T) return;
  const int l5 = threadIdx.x & 31;
  const int s = ts[t];
  const int r = tr[t];
  const int o = to[t];
  const u16x8 hs = *(const u16x8*)&hb[(size_t)s * DDIM + l5 * 8];
  const u16x8 ho = *(const u16x8*)&hb[(size_t)o * DDIM + l5 * 8];
  const float4 w0 = *(const float4*)&wrel[(size_t)r * DDIM + l5 * 8];
  const float4 w1 = *(const float4*)&wrel[(size_t)r * DDIM + l5 * 8 + 4];
  float sum = bf2f((unsigned short)hs[0]) * w0.x * bf2f((unsigned short)ho[0]) +
              bf2f((unsigned short)hs[1]) * w0.y * bf2f((unsigned short)ho[1]) +
              bf2f((unsigned short)hs[2]) * w0.z * bf2f((unsigned short)ho[2]) +
              bf2f((unsigned short)hs[3]) * w0.w * bf2f((unsigned short)ho[3]) +
              bf2f((unsigned short)hs[4]) * w1.x * bf2f((unsigned short)ho[4]) +
              bf2f((unsigned short)hs[5]) * w1.y * bf2f((unsigned short)ho[5]) +
              bf2f((unsigned short)hs[6]) * w1.z * bf2f((unsigned short)ho[6]) +
              bf2f((unsigned short)hs[7]) * w1.w * bf2f((unsigned short)ho[7]);
#pragma unroll
  for (int off = 16; off; off >>= 1) sum += __shfl_down(sum, off, 32);
  if (l5 == 0) out[t] = sum;
}

// ===========================================================================
extern "C" void kernel_launch(void* const* d_in, const int* in_sizes, int n_in,
                              void* d_out, int out_size, void* d_ws,
                              size_t ws_size, hipStream_t stream) {
  const float* feats = (const float*)d_in[0];
  const float* W_affine = (const float*)d_in[1];
  const float* b_affine = (const float*)d_in[2];
  const float* W_fwd = (const float*)d_in[3];
  const float* W_bwd = (const float*)d_in[4];
  const float* W_loop = (const float*)d_in[5];
  const float* w_relation = (const float*)d_in[6];
  const int* src = (const int*)d_in[7];
  const int* dst = (const int*)d_in[8];
  const int* etype = (const int*)d_in[9];
  const int* trip_s = (const int*)d_in[10];
  const int* trip_r = (const int*)d_in[11];
  const int* trip_o = (const int*)d_in[12];

  float* out_w = (float*)d_out;  // [N_TRIP]
  float* h = out_w + N_TRIP;     // [N_NODES * D] fp32

  char* ws = (char*)d_ws;
  unsigned short* fb = (unsigned short*)(ws);                 // 7,680,000
  unsigned short* Z = (unsigned short*)(ws + 7680000);        // 138,240,000
  unsigned short* hbf = (unsigned short*)(ws + 145920000);    // 15,360,000
  unsigned short* Wta = (unsigned short*)(ws + 161280000);    // 65,536
  unsigned short* Wcat1 = (unsigned short*)(ws + 161345536);  // 1,179,648
  unsigned short* Wcat2 = (unsigned short*)(ws + 162525184);  // 1,048,576
  int* cnt = (int*)(ws + 163573760);                          // 1,921,024
  int* offs = (int*)(ws + 165494784);                         // 1,921,024
  int* cur = (int*)(ws + 167415808);                          // 1,921,024
  int* bsum = (int*)(ws + 169336832);                         // 2,048
  int* gidx = (int*)(ws + 169338880);                         // 2,400,000

  // ---- edge bucketing ----
  zero_int_kernel<<<(NPAD + 255) / 256, 256, 0, stream>>>(cnt, NPAD);
  hist_kernel<<<(N_EDGES + 255) / 256, 256, 0, stream>>>(src, dst, etype, cnt);
  scan1_kernel<<<NCHUNK, 256, 0, stream>>>(cnt, offs, bsum);
  scan2_kernel<<<1, 512, 0, stream>>>(bsum);
  scan3_kernel<<<(NPAD + 255) / 256, 256, 0, stream>>>(offs, bsum, cur);
  fill_kernel<<<(N_EDGES + 255) / 256, 256, 0, stream>>>(src, dst, etype, cur,
                                                         gidx);

  // ---- conversions / weight prep ----
  convert_bf16_kernel<<<(N_NODES * F_RAW + 255) / 256, 256, 0, stream>>>(
      feats, fb, N_NODES * F_RAW);
  transpose_bf16_kernel<<<(F_RAW * DDIM + 255) / 256, 256, 0, stream>>>(
      W_affine, Wta, 1, F_RAW, DDIM);
  build_wcat2_kernel<<<(256 * KBIG + 255) / 256, 256, 0, stream>>>(
      W_fwd, W_loop, Wcat1, KBIG);
  build_wcat2_kernel<<<(256 * KBWD + 255) / 256, 256, 0, stream>>>(
      W_bwd, nullptr, Wcat2, KBWD);

  // ---- x -> Z cols [2048, 2304) ----
  const dim3 agrid(2, (N_NODES + 127) / 128);
  gemm128_kernel<<<agrid, 256, 0, stream>>>(fb, F_RAW, F_RAW, Wta, b_affine,
                                            Z + 2048, KBIG, N_NODES);

  const int nblk = 2 * ((N_NODES + 63) / 64);  // 938
  const int zgrid = (NUM_RELS * N_NODES + 7) / 8;

  // ---- Z_fwd cols [0,2048); h = [Z_fwd | x] @ [Wf ; Wl] ----
  zgatherw_kernel<<<zgrid, 256, 0, stream>>>(Z, 0, offs, gidx);
  gemm64_kernel<0><<<nblk, 256, 0, stream>>>(Z, KBIG, KBIG, Wcat1, h, nullptr,
                                             DDIM, N_NODES, nblk);
  // ---- Z_bwd overwrites cols [0,2048); h += Z_bwd @ [Wb], emit hbf ----
  zgatherw_kernel<<<zgrid, 256, 0, stream>>>(Z, 0, offs + NUM_RELS * N_NODES,
                                             gidx);
  gemm64_kernel<2><<<nblk, 256, 0, stream>>>(Z, KBIG, KBWD, Wcat2, h, hbf,
                                             DDIM, N_NODES, nblk);

  // ---- DistMult scoring ----
  score32_kernel<<<(N_TRIP + 7) / 8, 256, 0, stream>>>(
      hbf, w_relation, trip_s, trip_r, trip_o, out_w, N_TRIP);
}